// Round 1
// baseline (38.747 us; speedup 1.0000x reference)
//
#include <hip/hip_runtime.h>

// Problem shape (fixed by setup_inputs):
//   input: (256, 16) int32 in [0, 16384)  -> 4096 rows
//   out0:  one_hot(input, 16384)^2 == one_hot, float32, 256*16*16384 elems
//   out1:  pred = input, written as float32 (harness reads flat float buffer)
constexpr int  ROWS     = 256 * 16;            // 4096
constexpr int  DICT     = 16384;
constexpr long long P2_ELEMS = (long long)ROWS * DICT;   // 67,108,864 floats
constexpr long long P2_VEC4  = P2_ELEMS / 4;             // 16,777,216 float4 stores

__global__ __launch_bounds__(256) void onehot_scatter_kernel(
        const int* __restrict__ inp, float* __restrict__ out) {
    long long t = (long long)blockIdx.x * blockDim.x + threadIdx.x;  // [0, P2_VEC4)

    // Each row (one (i,j) pair) spans DICT/4 = 4096 float4 slots.
    int row = (int)(t >> 12);           // t / 4096
    int k4  = ((int)t & 4095) << 2;     // starting dict index of this float4
    int v   = inp[row];                 // broadcast load, cached

    float4 o;
    o.x = (k4     == v) ? 1.0f : 0.0f;
    o.y = (k4 + 1 == v) ? 1.0f : 0.0f;
    o.z = (k4 + 2 == v) ? 1.0f : 0.0f;
    o.w = (k4 + 3 == v) ? 1.0f : 0.0f;
    reinterpret_cast<float4*>(out)[t] = o;

    // pred = input, appended after the one-hot tensor, as float32.
    if (t < ROWS) {
        out[P2_ELEMS + t] = (float)inp[(int)t];
    }
}

extern "C" void kernel_launch(void* const* d_in, const int* in_sizes, int n_in,
                              void* d_out, int out_size, void* d_ws, size_t ws_size,
                              hipStream_t stream) {
    const int* inp = (const int*)d_in[0];   // (256,16) int32
    // d_in[1] = teacher_forcing scalar, unused (reference ignores it).
    float* out = (float*)d_out;

    const int block = 256;
    const long long grid = P2_VEC4 / block; // 65536 blocks, exact division
    onehot_scatter_kernel<<<(unsigned)grid, block, 0, stream>>>(inp, out);
}